// Round 11
// baseline (5639.964 us; speedup 1.0000x reference)
//
#include <hip/hip_runtime.h>

#define NVOX (128*128*128)
#define NK 45
#define NSL 48
#define LDSF 12288   // splat tile budget (floats) = 48 KB

// ---------------------------------------------------------------------------
// global-memory trilerp gather (reference semantics: OOB corners contribute 0)
__device__ __forceinline__ float trilerp_gather_g(const float* __restrict__ v,
                                                  float x, float y, float z)
{
    float x0f = floorf(x), y0f = floorf(y), z0f = floorf(z);
    int x0 = (int)x0f, y0 = (int)y0f, z0 = (int)z0f;
    float fx = x - x0f, fy = y - y0f, fz = z - z0f;

    if (((unsigned)x0 < 127u) & ((unsigned)y0 < 127u) & ((unsigned)z0 < 127u)) {
        const float* p = v + z0*16384 + y0*128 + x0;
        float v000 = p[0],     v001 = p[1];
        float v010 = p[128],   v011 = p[129];
        float v100 = p[16384], v101 = p[16385];
        float v110 = p[16512], v111 = p[16513];
        float c00 = v000 + fx*(v001 - v000);
        float c01 = v010 + fx*(v011 - v010);
        float c10 = v100 + fx*(v101 - v100);
        float c11 = v110 + fx*(v111 - v110);
        float c0  = c00 + fy*(c01 - c00);
        float c1  = c10 + fy*(c11 - c10);
        return c0 + fz*(c1 - c0);
    }
    if (x0 < -1 || x0 > 127 || y0 < -1 || y0 > 127 || z0 < -1 || z0 > 127)
        return 0.f;
    float acc = 0.f;
#pragma unroll
    for (int dz = 0; dz < 2; ++dz) {
        int zi = z0 + dz;
        if ((unsigned)zi >= 128u) continue;
        float wz = dz ? fz : 1.f - fz;
#pragma unroll
        for (int dy = 0; dy < 2; ++dy) {
            int yi = y0 + dy;
            if ((unsigned)yi >= 128u) continue;
            float wy = dy ? fy : 1.f - fy;
#pragma unroll
            for (int dx = 0; dx < 2; ++dx) {
                int xi = x0 + dx;
                if ((unsigned)xi >= 128u) continue;
                float wx = dx ? fx : 1.f - fx;
                acc += wz*wy*wx * v[zi*16384 + yi*128 + xi];
            }
        }
    }
    return acc;
}

// global-atomic splat (oversize-AABB fallback only)
__device__ __forceinline__ void trilerp_splat_g(float* __restrict__ v,
                                                float x, float y, float z, float val)
{
    float x0f = floorf(x), y0f = floorf(y), z0f = floorf(z);
    int x0 = (int)x0f, y0 = (int)y0f, z0 = (int)z0f;
    float fx = x - x0f, fy = y - y0f, fz = z - z0f;
    if (x0 < -1 || x0 > 127 || y0 < -1 || y0 > 127 || z0 < -1 || z0 > 127)
        return;
#pragma unroll
    for (int dz = 0; dz < 2; ++dz) {
        int zi = z0 + dz;
        if ((unsigned)zi >= 128u) continue;
        float wz = dz ? fz : 1.f - fz;
#pragma unroll
        for (int dy = 0; dy < 2; ++dy) {
            int yi = y0 + dy;
            if ((unsigned)yi >= 128u) continue;
            float wy = dy ? fy : 1.f - fy;
#pragma unroll
            for (int dx = 0; dx < 2; ++dx) {
                int xi = x0 + dx;
                if ((unsigned)xi >= 128u) continue;
                float wx = dx ? fx : 1.f - fx;
                unsafeAtomicAdd(v + zi*16384 + yi*128 + xi, val*wz*wy*wx);
            }
        }
    }
}

// ---------------------------------------------------------------------------
// precompute shift[n][k] = R_n @ off_k + t_n + center  (48*45*3 floats)
__global__ void k_shifts(const float* __restrict__ trans, float* __restrict__ shifts)
{
    int i = blockIdx.x * blockDim.x + threadIdx.x;
    if (i >= NSL * NK) return;
    int n = i / NK, k = i % NK;
    int kz = k / 9, ky = (k % 9) / 3, kx = k % 3;
    float ox = (float)(kx - 1);
    float oy = (float)(ky - 1);
    float oz = (float)(kz - 2);
    const float* T = trans + n * 12;
    shifts[i*3+0] = T[0]*ox + T[1]*oy + T[2]*oz  + T[3]  + 63.5f;
    shifts[i*3+1] = T[4]*ox + T[5]*oy + T[6]*oz  + T[7]  + 63.5f;
    shifts[i*3+2] = T[8]*ox + T[9]*oy + T[10]*oz + T[11] + 63.5f;
}

// ---------------------------------------------------------------------------
// reduction helper (256-thread blocks)
__device__ __forceinline__ void block_reduce_add(double s, double* out)
{
    for (int o = 32; o > 0; o >>= 1) s += __shfl_down(s, o);
    __shared__ double ls[4];
    int lane = threadIdx.x & 63, wid = threadIdx.x >> 6;
    if (lane == 0) ls[wid] = s;
    __syncthreads();
    if (threadIdx.x == 0) atomicAdd(out, ls[0] + ls[1] + ls[2] + ls[3]);
}

// ---------------------------------------------------------------------------
// A-side: val[n,h,w] = sum_k w_k * trilerp(vol, R*base + shift_k)
// Also zeroes ap_zero (grid-stride) and accumulates pAp = sum val^2 into pap.
// Blocks XCD-chunk-swizzled so each XCD's L2 holds a contiguous slice band.
__global__ __launch_bounds__(256) void k_gather(const float* __restrict__ vol,
                                                const float* __restrict__ shifts,
                                                const float* __restrict__ psf,
                                                const float* __restrict__ trans,
                                                float* __restrict__ val,
                                                float4* __restrict__ ap_zero,
                                                double* __restrict__ pap)
{
    __shared__ float sh[NK*4];
    int bid = blockIdx.x;
    int swz = (bid & 7) * (NSL * 64 / 8) + (bid >> 3);   // XCD-chunked swizzle
    int n = swz >> 6, seg = swz & 63, tid = threadIdx.x;

    // zero next AtA accumulator (completes before k_splat launch)
    int zi = bid * 256 + tid;
    if (zi < NVOX/4) ap_zero[zi] = make_float4(0.f, 0.f, 0.f, 0.f);

    for (int i = tid; i < NK*3; i += 256) sh[i] = shifts[n*NK*3 + i];
    if (tid < NK) sh[NK*3+tid] = psf[tid];
    const float* T = trans + n*12;
    float R00=T[0],R01=T[1],R10=T[4],R11=T[5],R20=T[8],R21=T[9];
    __syncthreads();

    int idx = seg*256 + tid;
    int h = idx >> 7, w = idx & 127;
    float bx = ((float)w - 63.5f)*1.25f;
    float by = ((float)h - 63.5f)*1.25f;
    float rbx = R00*bx + R01*by;
    float rby = R10*bx + R11*by;
    float rbz = R20*bx + R21*by;

    float s = 0.f;
#pragma unroll 3
    for (int k = 0; k < NK; ++k)
        s += sh[NK*3+k] * trilerp_gather_g(vol, rbx + sh[k*3], rby + sh[k*3+1],
                                           rbz + sh[k*3+2]);
    val[n*16384 + idx] = s;

    block_reduce_add((double)s * (double)s, pap);
}

// ---------------------------------------------------------------------------
// At-side: one WAVE per 16x16 tile, LDS slab accumulator, 4 parity phases.
// MODE 0: real — flush nonzero cells with global unsafeAtomicAdd.
// MODE 1: diagnostic — identical except flush uses PLAIN STORES (races on the
//         scratch target are fine; result unread). Isolates atomic-unit cost.
// MODE 2: diagnostic — accumulate only; token store keeps LDS live (no DCE).
template<int MODE>
__global__ __launch_bounds__(64) void k_splat(const float* __restrict__ val,
                                              float* __restrict__ pout,
                                              const float* __restrict__ shifts,
                                              const float* __restrict__ psf,
                                              const float* __restrict__ trans)
{
    __shared__ float tile[LDSF];
    __shared__ float sh[NK*4];
    int n = blockIdx.x >> 6, t2 = blockIdx.x & 63;
    int th = t2 >> 3, tw = t2 & 7;
    int lane = threadIdx.x;

    for (int i = lane; i < NK*3; i += 64) sh[i] = shifts[n*NK*3 + i];
    if (lane < NK) sh[NK*3+lane] = psf[lane];
    const float* T = trans + n*12;
    float R00=T[0],R01=T[1],R10=T[4],R11=T[5],R20=T[8],R21=T[9];
    __syncthreads();

    // AABB: lane-parallel min/max over the 45 tap shifts
    float sx0, sy0, sz0;
    if (lane < NK) { sx0 = sh[lane*3]; sy0 = sh[lane*3+1]; sz0 = sh[lane*3+2]; }
    else           { sx0 = sh[0];      sy0 = sh[1];        sz0 = sh[2]; }
    float sxmn=sx0,sxmx=sx0,symn=sy0,symx=sy0,szmn=sz0,szmx=sz0;
    for (int o = 32; o; o >>= 1) {
        sxmn = fminf(sxmn, __shfl_xor(sxmn,o)); sxmx = fmaxf(sxmx, __shfl_xor(sxmx,o));
        symn = fminf(symn, __shfl_xor(symn,o)); symx = fmaxf(symx, __shfl_xor(symx,o));
        szmn = fminf(szmn, __shfl_xor(szmn,o)); szmx = fmaxf(szmx, __shfl_xor(szmx,o));
    }
    float cbx = ((float)(tw*16) + 7.5f - 63.5f)*1.25f;
    float cby = ((float)(th*16) + 7.5f - 63.5f)*1.25f;
    const float hs = 9.375f;   // 7.5 * 1.25
    float cx = R00*cbx + R01*cby, hx = (fabsf(R00)+fabsf(R01))*hs;
    float cy = R10*cbx + R11*cby, hy = (fabsf(R10)+fabsf(R11))*hs;
    float cz = R20*cbx + R21*cby, hz = (fabsf(R20)+fabsf(R21))*hs;
    int x_lo = (int)floorf(cx-hx+sxmn), x_hi = (int)floorf(cx+hx+sxmx)+1;
    int y_lo = (int)floorf(cy-hy+symn), y_hi = (int)floorf(cy+hy+symx)+1;
    int z_lo = (int)floorf(cz-hz+szmn), z_hi = (int)floorf(cz+hz+szmx)+1;
    int dxs  = x_hi - x_lo + 1;
    dxs |= 1;                         // odd row stride (round-9 measured form)
    int dys  = y_hi - y_lo + 1;
    int dzs  = z_hi - z_lo + 1;
    int dxdy = dxs * dys;
    int total = dxdy * dzs;

    bool safe = (2.5f*(R00 - fabsf(R01)) >= 2.0f) &&
                (2.5f*(R11 - fabsf(R10)) >= 2.0f);

    if (total <= LDSF) {
        for (int c = lane; c < total; c += 64) tile[c] = 0.f;
        __syncthreads();

        // per-phase pixel geometry (fully unrolled -> registers)
        float prbx[4], prby[4], prbz[4], pval[4];
#pragma unroll
        for (int p = 0; p < 4; ++p) {
            int w = tw*16 + 2*(lane & 7)  + (p & 1);
            int h = th*16 + 2*(lane >> 3) + (p >> 1);
            float bx = ((float)w - 63.5f)*1.25f;
            float by = ((float)h - 63.5f)*1.25f;
            prbx[p] = R00*bx + R01*by;
            prby[p] = R10*bx + R11*by;
            prbz[p] = R20*bx + R21*by;
            pval[p] = val[n*16384 + (h<<7) + w];
        }

#pragma unroll 1
        for (int k = 0; k < NK; ++k) {
            float sx = sh[k*3], sy = sh[k*3+1], sz = sh[k*3+2], wk = sh[NK*3+k];
#pragma unroll
            for (int p = 0; p < 4; ++p) {
                float x = prbx[p] + sx, y = prby[p] + sy, z = prbz[p] + sz;
                float x0f = floorf(x), y0f = floorf(y), z0f = floorf(z);
                int lx = (int)x0f - x_lo, ly = (int)y0f - y_lo, lz = (int)z0f - z_lo;
                float fx = x - x0f, fy = y - y0f, fz = z - z0f;
                float vw = pval[p] * wk;
                float wx1 = fx, wx0 = 1.f - fx;
                float wy1 = fy, wy0 = 1.f - fy;
                float wz1 = fz, wz0 = 1.f - fz;
                float* q = tile + lz*dxdy + ly*dxs + lx;
                if (safe) {
                    q[0]          += vw*wz0*wy0*wx0;
                    q[1]          += vw*wz0*wy0*wx1;
                    q[dxs]        += vw*wz0*wy1*wx0;
                    q[dxs+1]      += vw*wz0*wy1*wx1;
                    q[dxdy]       += vw*wz1*wy0*wx0;
                    q[dxdy+1]     += vw*wz1*wy0*wx1;
                    q[dxdy+dxs]   += vw*wz1*wy1*wx0;
                    q[dxdy+dxs+1] += vw*wz1*wy1*wx1;
                } else {
                    atomicAdd(q,            vw*wz0*wy0*wx0);
                    atomicAdd(q+1,          vw*wz0*wy0*wx1);
                    atomicAdd(q+dxs,        vw*wz0*wy1*wx0);
                    atomicAdd(q+dxs+1,      vw*wz0*wy1*wx1);
                    atomicAdd(q+dxdy,       vw*wz1*wy0*wx0);
                    atomicAdd(q+dxdy+1,     vw*wz1*wy0*wx1);
                    atomicAdd(q+dxdy+dxs,   vw*wz1*wy1*wx0);
                    atomicAdd(q+dxdy+dxs+1, vw*wz1*wy1*wx1);
                }
            }
        }
        __syncthreads();

        if (MODE == 2) {
            // accumulate-only diagnostic: token store keeps tile live
            pout[blockIdx.x * 64 + lane] = tile[lane];
            return;
        }

        for (int c = lane; c < total; c += 64) {
            float v2 = tile[c];
            if (v2 != 0.f) {
                int lz = c / dxdy;
                int rem = c - lz*dxdy;
                int ly = rem / dxs;
                int lx = rem - ly*dxs;
                int gx = x_lo+lx, gy = y_lo+ly, gz = z_lo+lz;
                if (((unsigned)gx < 128u) & ((unsigned)gy < 128u) & ((unsigned)gz < 128u)) {
                    if (MODE == 0)
                        unsafeAtomicAdd(pout + gz*16384 + gy*128 + gx, v2);
                    else
                        pout[gz*16384 + gy*128 + gx] = v2;   // MODE 1: plain store
                }
            }
        }
    } else {
        // fallback: direct global-atomic splat
        for (int s2 = 0; s2 < 4; ++s2) {
            int px = s2*64 + lane;
            int ty = px >> 4, tx = px & 15;
            int h = th*16 + ty, w = tw*16 + tx;
            float bx = ((float)w - 63.5f)*1.25f;
            float by = ((float)h - 63.5f)*1.25f;
            float rbx = R00*bx + R01*by;
            float rby = R10*bx + R11*by;
            float rbz = R20*bx + R21*by;
            float v = val[n*16384 + (h<<7) + w];
#pragma unroll 1
            for (int k = 0; k < NK; ++k)
                trilerp_splat_g(pout, rbx + sh[k*3], rby + sh[k*3+1],
                                rbz + sh[k*3+2], sh[NK*3+k] * v);
        }
    }
}

// ---------------------------------------------------------------------------
// CG vector updates
__global__ __launch_bounds__(256) void k_init(const float* __restrict__ b,
                                              const float* __restrict__ Ax,
                                              float* __restrict__ r,
                                              float* __restrict__ p,
                                              double* rr0)
{
    double s = 0.0;
    for (int i = blockIdx.x * blockDim.x + threadIdx.x; i < NVOX;
         i += gridDim.x * blockDim.x) {
        float rv = b[i] - Ax[i];
        r[i] = rv;
        p[i] = rv;
        s += (double)rv * (double)rv;
    }
    block_reduce_add(s, rr0);
}

__global__ __launch_bounds__(256) void k_update_xr(float* __restrict__ x,
                                                   float* __restrict__ r,
                                                   const float* __restrict__ p,
                                                   const float* __restrict__ Ap,
                                                   const double* rr, const double* pap,
                                                   double* rrn, int do_r)
{
    float alpha = (float)(rr[0] / pap[0]);
    double s = 0.0;
    for (int i = blockIdx.x * blockDim.x + threadIdx.x; i < NVOX;
         i += gridDim.x * blockDim.x) {
        x[i] += alpha * p[i];
        if (do_r) {
            float rn = r[i] - alpha * Ap[i];
            r[i] = rn;
            s += (double)rn * (double)rn;
        }
    }
    block_reduce_add(s, rrn);
}

__global__ __launch_bounds__(256) void k_update_p(float* __restrict__ p,
                                                  const float* __restrict__ r,
                                                  const double* rrn, const double* rro)
{
    float beta = (float)(rrn[0] / rro[0]);
    for (int i = blockIdx.x * blockDim.x + threadIdx.x; i < NVOX;
         i += gridDim.x * blockDim.x)
        p[i] = r[i] + beta * p[i];
}

__global__ __launch_bounds__(256) void k_relu(const float* __restrict__ x,
                                              float* __restrict__ out)
{
    for (int i = blockIdx.x * blockDim.x + threadIdx.x; i < NVOX;
         i += gridDim.x * blockDim.x)
        out[i] = fmaxf(x[i], 0.f);
}

// ---------------------------------------------------------------------------
extern "C" void kernel_launch(void* const* d_in, const int* in_sizes, int n_in,
                              void* d_out, int out_size, void* d_ws, size_t ws_size,
                              hipStream_t stream)
{
    const float* vol    = (const float*)d_in[0];   // 128^3
    const float* slices = (const float*)d_in[1];   // 48*128*128
    const float* trans  = (const float*)d_in[2];   // 48*3*4
    const float* psf    = (const float*)d_in[3];   // 45
    float* out = (float*)d_out;

    const size_t VB = (size_t)NVOX * 4;            // 8 MB
    char* w = (char*)d_ws;
    float* x      = (float*)(w);
    float* b      = (float*)(w + VB);
    float* r      = (float*)(w + VB*2);
    float* p      = (float*)(w + VB*3);
    float* Ap     = (float*)(w + VB*4);
    float* shifts = (float*)(w + VB*5);            // 25920 B
    double* sc    = (double*)(w + VB*5 + 32768);   // 22 doubles
    float* val    = (float*)(w + VB*6);            // 48*16384 floats = 3 MB
    float* diag   = (float*)(w + VB*7);            // diagnostic scratch volume
    // sc[0..10] = rr_i, sc[11..20] = pAp_i, sc[21] = dummy pAp for initial AtA

    hipMemsetAsync(sc, 0, 22 * sizeof(double), stream);
    hipLaunchKernelGGL(k_shifts, dim3(9), dim3(256), 0, stream, trans, shifts);

    // --- diagnostics (once, on scratch): isolate flush-atomic vs LDS-RMW cost
    if (ws_size >= VB * 8) {
        hipLaunchKernelGGL(k_splat<1>, dim3(NSL * 64), dim3(64), 0, stream,
                           slices, diag, shifts, psf, trans);
        hipLaunchKernelGGL(k_splat<2>, dim3(NSL * 64), dim3(64), 0, stream,
                           slices, diag, shifts, psf, trans);
    }

    // b = At(y): slices already have the val layout — splat directly
    hipMemsetAsync(b, 0, VB, stream);
    hipLaunchKernelGGL(k_splat<0>, dim3(NSL * 64), dim3(64), 0, stream,
                       slices, b, shifts, psf, trans);

    // x = vol (initial guess)
    hipMemcpyAsync(x, vol, VB, hipMemcpyDeviceToDevice, stream);

    // Ax = AtA(x)  (k_gather zeroes Ap and computes a dummy pAp)
    hipLaunchKernelGGL(k_gather, dim3(NSL * 64), dim3(256), 0, stream,
                       x, shifts, psf, trans, val, (float4*)Ap, sc + 21);
    hipLaunchKernelGGL(k_splat<0>, dim3(NSL * 64), dim3(64), 0, stream,
                       val, Ap, shifts, psf, trans);

    // r = b - Ax; p = r; rr0 = <r,r>
    hipLaunchKernelGGL(k_init, dim3(512), dim3(256), 0, stream, b, Ap, r, p, sc + 0);

    for (int i = 0; i < 10; ++i) {
        // gather: val = A p, Ap := 0, pAp_i = sum(val^2) == <p, AtA p>
        hipLaunchKernelGGL(k_gather, dim3(NSL * 64), dim3(256), 0, stream,
                           p, shifts, psf, trans, val, (float4*)Ap, sc + 11 + i);
        hipLaunchKernelGGL(k_splat<0>, dim3(NSL * 64), dim3(64), 0, stream,
                           val, Ap, shifts, psf, trans);
        hipLaunchKernelGGL(k_update_xr, dim3(512), dim3(256), 0, stream,
                           x, r, p, Ap, sc + i, sc + 11 + i, sc + i + 1, (int)(i < 9));
        if (i < 9)
            hipLaunchKernelGGL(k_update_p, dim3(512), dim3(256), 0, stream,
                               p, r, sc + i + 1, sc + i);
    }

    hipLaunchKernelGGL(k_relu, dim3(512), dim3(256), 0, stream, x, out);
}

// Round 12
// 4711.732 us; speedup vs baseline: 1.1970x; 1.1970x over previous
//
#include <hip/hip_runtime.h>

#define NVOX (128*128*128)
#define NK 45
#define NSL 48
#define LDSF 9800    // per-group slab budget (floats) = 39.2 KB -> 4 blocks/CU

// ---------------------------------------------------------------------------
// global-memory trilerp gather (reference semantics: OOB corners contribute 0)
__device__ __forceinline__ float trilerp_gather_g(const float* __restrict__ v,
                                                  float x, float y, float z)
{
    float x0f = floorf(x), y0f = floorf(y), z0f = floorf(z);
    int x0 = (int)x0f, y0 = (int)y0f, z0 = (int)z0f;
    float fx = x - x0f, fy = y - y0f, fz = z - z0f;

    if (((unsigned)x0 < 127u) & ((unsigned)y0 < 127u) & ((unsigned)z0 < 127u)) {
        const float* p = v + z0*16384 + y0*128 + x0;
        float v000 = p[0],     v001 = p[1];
        float v010 = p[128],   v011 = p[129];
        float v100 = p[16384], v101 = p[16385];
        float v110 = p[16512], v111 = p[16513];
        float c00 = v000 + fx*(v001 - v000);
        float c01 = v010 + fx*(v011 - v010);
        float c10 = v100 + fx*(v101 - v100);
        float c11 = v110 + fx*(v111 - v110);
        float c0  = c00 + fy*(c01 - c00);
        float c1  = c10 + fy*(c11 - c10);
        return c0 + fz*(c1 - c0);
    }
    if (x0 < -1 || x0 > 127 || y0 < -1 || y0 > 127 || z0 < -1 || z0 > 127)
        return 0.f;
    float acc = 0.f;
#pragma unroll
    for (int dz = 0; dz < 2; ++dz) {
        int zi = z0 + dz;
        if ((unsigned)zi >= 128u) continue;
        float wz = dz ? fz : 1.f - fz;
#pragma unroll
        for (int dy = 0; dy < 2; ++dy) {
            int yi = y0 + dy;
            if ((unsigned)yi >= 128u) continue;
            float wy = dy ? fy : 1.f - fy;
#pragma unroll
            for (int dx = 0; dx < 2; ++dx) {
                int xi = x0 + dx;
                if ((unsigned)xi >= 128u) continue;
                float wx = dx ? fx : 1.f - fx;
                acc += wz*wy*wx * v[zi*16384 + yi*128 + xi];
            }
        }
    }
    return acc;
}

// global-atomic splat (oversize-AABB fallback only)
__device__ __forceinline__ void trilerp_splat_g(float* __restrict__ v,
                                                float x, float y, float z, float val)
{
    float x0f = floorf(x), y0f = floorf(y), z0f = floorf(z);
    int x0 = (int)x0f, y0 = (int)y0f, z0 = (int)z0f;
    float fx = x - x0f, fy = y - y0f, fz = z - z0f;
    if (x0 < -1 || x0 > 127 || y0 < -1 || y0 > 127 || z0 < -1 || z0 > 127)
        return;
#pragma unroll
    for (int dz = 0; dz < 2; ++dz) {
        int zi = z0 + dz;
        if ((unsigned)zi >= 128u) continue;
        float wz = dz ? fz : 1.f - fz;
#pragma unroll
        for (int dy = 0; dy < 2; ++dy) {
            int yi = y0 + dy;
            if ((unsigned)yi >= 128u) continue;
            float wy = dy ? fy : 1.f - fy;
#pragma unroll
            for (int dx = 0; dx < 2; ++dx) {
                int xi = x0 + dx;
                if ((unsigned)xi >= 128u) continue;
                float wx = dx ? fx : 1.f - fx;
                unsafeAtomicAdd(v + zi*16384 + yi*128 + xi, val*wz*wy*wx);
            }
        }
    }
}

// ---------------------------------------------------------------------------
// precompute shift[n][k] = R_n @ off_k + t_n + center  (48*45*3 floats)
__global__ void k_shifts(const float* __restrict__ trans, float* __restrict__ shifts)
{
    int i = blockIdx.x * blockDim.x + threadIdx.x;
    if (i >= NSL * NK) return;
    int n = i / NK, k = i % NK;
    int kz = k / 9, ky = (k % 9) / 3, kx = k % 3;
    float ox = (float)(kx - 1);
    float oy = (float)(ky - 1);
    float oz = (float)(kz - 2);
    const float* T = trans + n * 12;
    shifts[i*3+0] = T[0]*ox + T[1]*oy + T[2]*oz  + T[3]  + 63.5f;
    shifts[i*3+1] = T[4]*ox + T[5]*oy + T[6]*oz  + T[7]  + 63.5f;
    shifts[i*3+2] = T[8]*ox + T[9]*oy + T[10]*oz + T[11] + 63.5f;
}

// ---------------------------------------------------------------------------
// reduction helper (256-thread blocks)
__device__ __forceinline__ void block_reduce_add(double s, double* out)
{
    for (int o = 32; o > 0; o >>= 1) s += __shfl_down(s, o);
    __shared__ double ls[4];
    int lane = threadIdx.x & 63, wid = threadIdx.x >> 6;
    if (lane == 0) ls[wid] = s;
    __syncthreads();
    if (threadIdx.x == 0) atomicAdd(out, ls[0] + ls[1] + ls[2] + ls[3]);
}

// ---------------------------------------------------------------------------
// A-side: val[n,h,w] = sum_k w_k * trilerp(vol, R*base + shift_k)
// Also zeroes ap_zero (grid-stride) and accumulates pAp = sum val^2 into pap.
// Blocks XCD-chunk-swizzled so each XCD's L2 holds a contiguous slice band.
__global__ __launch_bounds__(256) void k_gather(const float* __restrict__ vol,
                                                const float* __restrict__ shifts,
                                                const float* __restrict__ psf,
                                                const float* __restrict__ trans,
                                                float* __restrict__ val,
                                                float4* __restrict__ ap_zero,
                                                double* __restrict__ pap)
{
    __shared__ float sh[NK*4];
    int bid = blockIdx.x;
    int swz = (bid & 7) * (NSL * 64 / 8) + (bid >> 3);   // XCD-chunked swizzle
    int n = swz >> 6, seg = swz & 63, tid = threadIdx.x;

    // zero next AtA accumulator (completes before k_splat launch)
    int zi = bid * 256 + tid;
    if (zi < NVOX/4) ap_zero[zi] = make_float4(0.f, 0.f, 0.f, 0.f);

    for (int i = tid; i < NK*3; i += 256) sh[i] = shifts[n*NK*3 + i];
    if (tid < NK) sh[NK*3+tid] = psf[tid];
    const float* T = trans + n*12;
    float R00=T[0],R01=T[1],R10=T[4],R11=T[5],R20=T[8],R21=T[9];
    __syncthreads();

    int idx = seg*256 + tid;
    int h = idx >> 7, w = idx & 127;
    float bx = ((float)w - 63.5f)*1.25f;
    float by = ((float)h - 63.5f)*1.25f;
    float rbx = R00*bx + R01*by;
    float rby = R10*bx + R11*by;
    float rbz = R20*bx + R21*by;

    float s = 0.f;
#pragma unroll 3
    for (int k = 0; k < NK; ++k)
        s += sh[NK*3+k] * trilerp_gather_g(vol, rbx + sh[k*3], rby + sh[k*3+1],
                                           rbz + sh[k*3+2]);
    val[n*16384 + idx] = s;

    block_reduce_add((double)s * (double)s, pap);
}

// ---------------------------------------------------------------------------
// At-side: one WAVE per (16x16 tile, kz-group), LDS slab accumulator, 4 parity
// phases. blockIdx.y selects the kz-group: group 0 = taps k<27 (kz 0..2),
// group 1 = k>=27 (kz 3,4). Halved z-extent -> ~39KB slab -> 4 blocks/CU.
// Race-free non-atomic RMW: within a phase, active pixels differ by even
// pixel steps => projected 2x2x2 corner boxes disjoint (|dX| >=
// 2.5*(R00-|R01|) >= 2 when |dw|>=|dh|, symmetric in y; runtime-checked).
__global__ __launch_bounds__(64) void k_splat(const float* __restrict__ val,
                                              float* __restrict__ pout,
                                              const float* __restrict__ shifts,
                                              const float* __restrict__ psf,
                                              const float* __restrict__ trans)
{
    __shared__ float tile[LDSF];
    __shared__ float sh[NK*4];
    int n = blockIdx.x >> 6, t2 = blockIdx.x & 63;
    int th = t2 >> 3, tw = t2 & 7;
    int lane = threadIdx.x;
    int kbeg = blockIdx.y ? 27 : 0;
    int kend = blockIdx.y ? NK : 27;
    int kcnt = kend - kbeg;

    for (int i = lane; i < NK*3; i += 64) sh[i] = shifts[n*NK*3 + i];
    if (lane < NK) sh[NK*3+lane] = psf[lane];
    const float* T = trans + n*12;
    float R00=T[0],R01=T[1],R10=T[4],R11=T[5],R20=T[8],R21=T[9];
    __syncthreads();

    // AABB over THIS GROUP's tap shifts (lane-parallel min/max)
    int kl = kbeg + ((lane < kcnt) ? lane : 0);
    float sx0 = sh[kl*3], sy0 = sh[kl*3+1], sz0 = sh[kl*3+2];
    float sxmn=sx0,sxmx=sx0,symn=sy0,symx=sy0,szmn=sz0,szmx=sz0;
    for (int o = 32; o; o >>= 1) {
        sxmn = fminf(sxmn, __shfl_xor(sxmn,o)); sxmx = fmaxf(sxmx, __shfl_xor(sxmx,o));
        symn = fminf(symn, __shfl_xor(symn,o)); symx = fmaxf(symx, __shfl_xor(symx,o));
        szmn = fminf(szmn, __shfl_xor(szmn,o)); szmx = fmaxf(szmx, __shfl_xor(szmx,o));
    }
    float cbx = ((float)(tw*16) + 7.5f - 63.5f)*1.25f;
    float cby = ((float)(th*16) + 7.5f - 63.5f)*1.25f;
    const float hs = 9.375f;   // 7.5 * 1.25
    float cx = R00*cbx + R01*cby, hx = (fabsf(R00)+fabsf(R01))*hs;
    float cy = R10*cbx + R11*cby, hy = (fabsf(R10)+fabsf(R11))*hs;
    float cz = R20*cbx + R21*cby, hz = (fabsf(R20)+fabsf(R21))*hs;
    int x_lo = (int)floorf(cx-hx+sxmn), x_hi = (int)floorf(cx+hx+sxmx)+1;
    int y_lo = (int)floorf(cy-hy+symn), y_hi = (int)floorf(cy+hy+symx)+1;
    int z_lo = (int)floorf(cz-hz+szmn), z_hi = (int)floorf(cz+hz+szmx)+1;
    int dxs  = x_hi - x_lo + 1;
    dxs |= 1;                         // odd row stride
    int dys  = y_hi - y_lo + 1;
    int dzs  = z_hi - z_lo + 1;
    int dxdy = dxs * dys;
    int total = dxdy * dzs;

    bool safe = (2.5f*(R00 - fabsf(R01)) >= 2.0f) &&
                (2.5f*(R11 - fabsf(R10)) >= 2.0f);

    if (total <= LDSF) {
        for (int c = lane; c < total; c += 64) tile[c] = 0.f;
        __syncthreads();

        // per-phase pixel geometry (fully unrolled -> registers)
        float prbx[4], prby[4], prbz[4], pval[4];
#pragma unroll
        for (int p = 0; p < 4; ++p) {
            int w = tw*16 + 2*(lane & 7)  + (p & 1);
            int h = th*16 + 2*(lane >> 3) + (p >> 1);
            float bx = ((float)w - 63.5f)*1.25f;
            float by = ((float)h - 63.5f)*1.25f;
            prbx[p] = R00*bx + R01*by;
            prby[p] = R10*bx + R11*by;
            prbz[p] = R20*bx + R21*by;
            pval[p] = val[n*16384 + (h<<7) + w];
        }

#pragma unroll 1
        for (int k = kbeg; k < kend; ++k) {
            float sx = sh[k*3], sy = sh[k*3+1], sz = sh[k*3+2], wk = sh[NK*3+k];
#pragma unroll
            for (int p = 0; p < 4; ++p) {
                float x = prbx[p] + sx, y = prby[p] + sy, z = prbz[p] + sz;
                float x0f = floorf(x), y0f = floorf(y), z0f = floorf(z);
                int lx = (int)x0f - x_lo, ly = (int)y0f - y_lo, lz = (int)z0f - z_lo;
                float fx = x - x0f, fy = y - y0f, fz = z - z0f;
                float vw = pval[p] * wk;
                float wx1 = fx, wx0 = 1.f - fx;
                float wy1 = fy, wy0 = 1.f - fy;
                float wz1 = fz, wz0 = 1.f - fz;
                float* q = tile + lz*dxdy + ly*dxs + lx;
                if (safe) {
                    q[0]          += vw*wz0*wy0*wx0;
                    q[1]          += vw*wz0*wy0*wx1;
                    q[dxs]        += vw*wz0*wy1*wx0;
                    q[dxs+1]      += vw*wz0*wy1*wx1;
                    q[dxdy]       += vw*wz1*wy0*wx0;
                    q[dxdy+1]     += vw*wz1*wy0*wx1;
                    q[dxdy+dxs]   += vw*wz1*wy1*wx0;
                    q[dxdy+dxs+1] += vw*wz1*wy1*wx1;
                } else {
                    atomicAdd(q,            vw*wz0*wy0*wx0);
                    atomicAdd(q+1,          vw*wz0*wy0*wx1);
                    atomicAdd(q+dxs,        vw*wz0*wy1*wx0);
                    atomicAdd(q+dxs+1,      vw*wz0*wy1*wx1);
                    atomicAdd(q+dxdy,       vw*wz1*wy0*wx0);
                    atomicAdd(q+dxdy+1,     vw*wz1*wy0*wx1);
                    atomicAdd(q+dxdy+dxs,   vw*wz1*wy1*wx0);
                    atomicAdd(q+dxdy+dxs+1, vw*wz1*wy1*wx1);
                }
            }
        }
        __syncthreads();

        for (int c = lane; c < total; c += 64) {
            float v2 = tile[c];
            if (v2 != 0.f) {
                int lz = c / dxdy;
                int rem = c - lz*dxdy;
                int ly = rem / dxs;
                int lx = rem - ly*dxs;
                int gx = x_lo+lx, gy = y_lo+ly, gz = z_lo+lz;
                if (((unsigned)gx < 128u) & ((unsigned)gy < 128u) & ((unsigned)gz < 128u))
                    unsafeAtomicAdd(pout + gz*16384 + gy*128 + gx, v2);
            }
        }
    } else {
        // fallback: direct global-atomic splat for THIS GROUP's taps
        for (int s2 = 0; s2 < 4; ++s2) {
            int px = s2*64 + lane;
            int ty = px >> 4, tx = px & 15;
            int h = th*16 + ty, w = tw*16 + tx;
            float bx = ((float)w - 63.5f)*1.25f;
            float by = ((float)h - 63.5f)*1.25f;
            float rbx = R00*bx + R01*by;
            float rby = R10*bx + R11*by;
            float rbz = R20*bx + R21*by;
            float v = val[n*16384 + (h<<7) + w];
#pragma unroll 1
            for (int k = kbeg; k < kend; ++k)
                trilerp_splat_g(pout, rbx + sh[k*3], rby + sh[k*3+1],
                                rbz + sh[k*3+2], sh[NK*3+k] * v);
        }
    }
}

// ---------------------------------------------------------------------------
// CG vector updates
__global__ __launch_bounds__(256) void k_init(const float* __restrict__ b,
                                              const float* __restrict__ Ax,
                                              float* __restrict__ r,
                                              float* __restrict__ p,
                                              double* rr0)
{
    double s = 0.0;
    for (int i = blockIdx.x * blockDim.x + threadIdx.x; i < NVOX;
         i += gridDim.x * blockDim.x) {
        float rv = b[i] - Ax[i];
        r[i] = rv;
        p[i] = rv;
        s += (double)rv * (double)rv;
    }
    block_reduce_add(s, rr0);
}

__global__ __launch_bounds__(256) void k_update_xr(float* __restrict__ x,
                                                   float* __restrict__ r,
                                                   const float* __restrict__ p,
                                                   const float* __restrict__ Ap,
                                                   const double* rr, const double* pap,
                                                   double* rrn, int do_r)
{
    float alpha = (float)(rr[0] / pap[0]);
    double s = 0.0;
    for (int i = blockIdx.x * blockDim.x + threadIdx.x; i < NVOX;
         i += gridDim.x * blockDim.x) {
        x[i] += alpha * p[i];
        if (do_r) {
            float rn = r[i] - alpha * Ap[i];
            r[i] = rn;
            s += (double)rn * (double)rn;
        }
    }
    block_reduce_add(s, rrn);
}

__global__ __launch_bounds__(256) void k_update_p(float* __restrict__ p,
                                                  const float* __restrict__ r,
                                                  const double* rrn, const double* rro)
{
    float beta = (float)(rrn[0] / rro[0]);
    for (int i = blockIdx.x * blockDim.x + threadIdx.x; i < NVOX;
         i += gridDim.x * blockDim.x)
        p[i] = r[i] + beta * p[i];
}

__global__ __launch_bounds__(256) void k_relu(const float* __restrict__ x,
                                              float* __restrict__ out)
{
    for (int i = blockIdx.x * blockDim.x + threadIdx.x; i < NVOX;
         i += gridDim.x * blockDim.x)
        out[i] = fmaxf(x[i], 0.f);
}

// ---------------------------------------------------------------------------
extern "C" void kernel_launch(void* const* d_in, const int* in_sizes, int n_in,
                              void* d_out, int out_size, void* d_ws, size_t ws_size,
                              hipStream_t stream)
{
    const float* vol    = (const float*)d_in[0];   // 128^3
    const float* slices = (const float*)d_in[1];   // 48*128*128
    const float* trans  = (const float*)d_in[2];   // 48*3*4
    const float* psf    = (const float*)d_in[3];   // 45
    float* out = (float*)d_out;

    const size_t VB = (size_t)NVOX * 4;            // 8 MB
    char* w = (char*)d_ws;
    float* x      = (float*)(w);
    float* b      = (float*)(w + VB);
    float* r      = (float*)(w + VB*2);
    float* p      = (float*)(w + VB*3);
    float* Ap     = (float*)(w + VB*4);
    float* shifts = (float*)(w + VB*5);            // 25920 B
    double* sc    = (double*)(w + VB*5 + 32768);   // 22 doubles
    float* val    = (float*)(w + VB*6);            // 48*16384 floats = 3 MB
    // sc[0..10] = rr_i, sc[11..20] = pAp_i, sc[21] = dummy pAp for initial AtA

    hipMemsetAsync(sc, 0, 22 * sizeof(double), stream);
    hipLaunchKernelGGL(k_shifts, dim3(9), dim3(256), 0, stream, trans, shifts);

    // b = At(y): slices already have the val layout — splat directly
    hipMemsetAsync(b, 0, VB, stream);
    hipLaunchKernelGGL(k_splat, dim3(NSL * 64, 2), dim3(64), 0, stream,
                       slices, b, shifts, psf, trans);

    // x = vol (initial guess)
    hipMemcpyAsync(x, vol, VB, hipMemcpyDeviceToDevice, stream);

    // Ax = AtA(x)  (k_gather zeroes Ap and computes a dummy pAp)
    hipLaunchKernelGGL(k_gather, dim3(NSL * 64), dim3(256), 0, stream,
                       x, shifts, psf, trans, val, (float4*)Ap, sc + 21);
    hipLaunchKernelGGL(k_splat, dim3(NSL * 64, 2), dim3(64), 0, stream,
                       val, Ap, shifts, psf, trans);

    // r = b - Ax; p = r; rr0 = <r,r>
    hipLaunchKernelGGL(k_init, dim3(512), dim3(256), 0, stream, b, Ap, r, p, sc + 0);

    for (int i = 0; i < 10; ++i) {
        // gather: val = A p, Ap := 0, pAp_i = sum(val^2) == <p, AtA p>
        hipLaunchKernelGGL(k_gather, dim3(NSL * 64), dim3(256), 0, stream,
                           p, shifts, psf, trans, val, (float4*)Ap, sc + 11 + i);
        hipLaunchKernelGGL(k_splat, dim3(NSL * 64, 2), dim3(64), 0, stream,
                           val, Ap, shifts, psf, trans);
        hipLaunchKernelGGL(k_update_xr, dim3(512), dim3(256), 0, stream,
                           x, r, p, Ap, sc + i, sc + 11 + i, sc + i + 1, (int)(i < 9));
        if (i < 9)
            hipLaunchKernelGGL(k_update_p, dim3(512), dim3(256), 0, stream,
                               p, r, sc + i + 1, sc + i);
    }

    hipLaunchKernelGGL(k_relu, dim3(512), dim3(256), 0, stream, x, out);
}

// Round 13
// 4164.714 us; speedup vs baseline: 1.3542x; 1.1313x over previous
//
#include <hip/hip_runtime.h>

#define NVOX (128*128*128)
#define NK 45
#define NSL 48
#define LDSF 9800    // per-group slab budget (floats) = 39.2 KB -> 4 blocks/CU

// ---------------------------------------------------------------------------
// global-memory trilerp gather (reference semantics: OOB corners contribute 0)
__device__ __forceinline__ float trilerp_gather_g(const float* __restrict__ v,
                                                  float x, float y, float z)
{
    float x0f = floorf(x), y0f = floorf(y), z0f = floorf(z);
    int x0 = (int)x0f, y0 = (int)y0f, z0 = (int)z0f;
    float fx = x - x0f, fy = y - y0f, fz = z - z0f;

    if (((unsigned)x0 < 127u) & ((unsigned)y0 < 127u) & ((unsigned)z0 < 127u)) {
        const float* p = v + z0*16384 + y0*128 + x0;
        float v000 = p[0],     v001 = p[1];
        float v010 = p[128],   v011 = p[129];
        float v100 = p[16384], v101 = p[16385];
        float v110 = p[16512], v111 = p[16513];
        float c00 = v000 + fx*(v001 - v000);
        float c01 = v010 + fx*(v011 - v010);
        float c10 = v100 + fx*(v101 - v100);
        float c11 = v110 + fx*(v111 - v110);
        float c0  = c00 + fy*(c01 - c00);
        float c1  = c10 + fy*(c11 - c10);
        return c0 + fz*(c1 - c0);
    }
    if (x0 < -1 || x0 > 127 || y0 < -1 || y0 > 127 || z0 < -1 || z0 > 127)
        return 0.f;
    float acc = 0.f;
#pragma unroll
    for (int dz = 0; dz < 2; ++dz) {
        int zi = z0 + dz;
        if ((unsigned)zi >= 128u) continue;
        float wz = dz ? fz : 1.f - fz;
#pragma unroll
        for (int dy = 0; dy < 2; ++dy) {
            int yi = y0 + dy;
            if ((unsigned)yi >= 128u) continue;
            float wy = dy ? fy : 1.f - fy;
#pragma unroll
            for (int dx = 0; dx < 2; ++dx) {
                int xi = x0 + dx;
                if ((unsigned)xi >= 128u) continue;
                float wx = dx ? fx : 1.f - fx;
                acc += wz*wy*wx * v[zi*16384 + yi*128 + xi];
            }
        }
    }
    return acc;
}

// global-atomic splat (oversize-AABB fallback only)
__device__ __forceinline__ void trilerp_splat_g(float* __restrict__ v,
                                                float x, float y, float z, float val)
{
    float x0f = floorf(x), y0f = floorf(y), z0f = floorf(z);
    int x0 = (int)x0f, y0 = (int)y0f, z0 = (int)z0f;
    float fx = x - x0f, fy = y - y0f, fz = z - z0f;
    if (x0 < -1 || x0 > 127 || y0 < -1 || y0 > 127 || z0 < -1 || z0 > 127)
        return;
#pragma unroll
    for (int dz = 0; dz < 2; ++dz) {
        int zi = z0 + dz;
        if ((unsigned)zi >= 128u) continue;
        float wz = dz ? fz : 1.f - fz;
#pragma unroll
        for (int dy = 0; dy < 2; ++dy) {
            int yi = y0 + dy;
            if ((unsigned)yi >= 128u) continue;
            float wy = dy ? fy : 1.f - fy;
#pragma unroll
            for (int dx = 0; dx < 2; ++dx) {
                int xi = x0 + dx;
                if ((unsigned)xi >= 128u) continue;
                float wx = dx ? fx : 1.f - fx;
                unsafeAtomicAdd(v + zi*16384 + yi*128 + xi, val*wz*wy*wx);
            }
        }
    }
}

// ---------------------------------------------------------------------------
// precompute shift[n][k] = R_n @ off_k + t_n + center  (48*45*3 floats)
__global__ void k_shifts(const float* __restrict__ trans, float* __restrict__ shifts)
{
    int i = blockIdx.x * blockDim.x + threadIdx.x;
    if (i >= NSL * NK) return;
    int n = i / NK, k = i % NK;
    int kz = k / 9, ky = (k % 9) / 3, kx = k % 3;
    float ox = (float)(kx - 1);
    float oy = (float)(ky - 1);
    float oz = (float)(kz - 2);
    const float* T = trans + n * 12;
    shifts[i*3+0] = T[0]*ox + T[1]*oy + T[2]*oz  + T[3]  + 63.5f;
    shifts[i*3+1] = T[4]*ox + T[5]*oy + T[6]*oz  + T[7]  + 63.5f;
    shifts[i*3+2] = T[8]*ox + T[9]*oy + T[10]*oz + T[11] + 63.5f;
}

// ---------------------------------------------------------------------------
// reduction helper (256-thread blocks)
__device__ __forceinline__ void block_reduce_add(double s, double* out)
{
    for (int o = 32; o > 0; o >>= 1) s += __shfl_down(s, o);
    __shared__ double ls[4];
    int lane = threadIdx.x & 63, wid = threadIdx.x >> 6;
    if (lane == 0) ls[wid] = s;
    __syncthreads();
    if (threadIdx.x == 0) atomicAdd(out, ls[0] + ls[1] + ls[2] + ls[3]);
}

// ---------------------------------------------------------------------------
// A-side: val[n,h,w] = sum_k w_k * trilerp(vol, R*base + shift_k)
// Also zeroes ap_zero (grid-stride) and accumulates pAp = sum val^2 into pap.
__global__ __launch_bounds__(256) void k_gather(const float* __restrict__ vol,
                                                const float* __restrict__ shifts,
                                                const float* __restrict__ psf,
                                                const float* __restrict__ trans,
                                                float* __restrict__ val,
                                                float4* __restrict__ ap_zero,
                                                double* __restrict__ pap)
{
    __shared__ float sh[NK*4];
    int bid = blockIdx.x;
    int swz = (bid & 7) * (NSL * 64 / 8) + (bid >> 3);   // XCD-chunked swizzle
    int n = swz >> 6, seg = swz & 63, tid = threadIdx.x;

    // zero next AtA accumulator (completes before k_splat launch)
    int zi = bid * 256 + tid;
    if (zi < NVOX/4) ap_zero[zi] = make_float4(0.f, 0.f, 0.f, 0.f);

    for (int i = tid; i < NK*3; i += 256) sh[i] = shifts[n*NK*3 + i];
    if (tid < NK) sh[NK*3+tid] = psf[tid];
    const float* T = trans + n*12;
    float R00=T[0],R01=T[1],R10=T[4],R11=T[5],R20=T[8],R21=T[9];
    __syncthreads();

    int idx = seg*256 + tid;
    int h = idx >> 7, w = idx & 127;
    float bx = ((float)w - 63.5f)*1.25f;
    float by = ((float)h - 63.5f)*1.25f;
    float rbx = R00*bx + R01*by;
    float rby = R10*bx + R11*by;
    float rbz = R20*bx + R21*by;

    float s = 0.f;
#pragma unroll 3
    for (int k = 0; k < NK; ++k)
        s += sh[NK*3+k] * trilerp_gather_g(vol, rbx + sh[k*3], rby + sh[k*3+1],
                                           rbz + sh[k*3+2]);
    val[n*16384 + idx] = s;

    block_reduce_add((double)s * (double)s, pap);
}

// ---------------------------------------------------------------------------
// At-side: one WAVE per (16x16 tile, kz-group), LDS slab accumulator, 4 parity
// phases. blockIdx.y selects the kz-group (k<27 / k>=27). Race-free
// non-atomic RMW: within a phase, active pixels differ by even pixel steps =>
// projected 2x2x2 corner boxes disjoint (runtime-checked `safe`). The RMW is
// hand-batched (8 reads -> 8 adds -> 8 writes) so the compiler issues all 8
// ds_reads before one wait, instead of serializing per-cell on unprovable
// aliasing of runtime offsets. Cross-phase RAW safety: per-wave DS ops
// execute in order; compiler keeps program order for maybe-aliasing LDS ops.
__global__ __launch_bounds__(64) void k_splat(const float* __restrict__ val,
                                              float* __restrict__ pout,
                                              const float* __restrict__ shifts,
                                              const float* __restrict__ psf,
                                              const float* __restrict__ trans)
{
    __shared__ float tile[LDSF];
    __shared__ float sh[NK*4];
    int n = blockIdx.x >> 6, t2 = blockIdx.x & 63;
    int th = t2 >> 3, tw = t2 & 7;
    int lane = threadIdx.x;
    int kbeg = blockIdx.y ? 27 : 0;
    int kend = blockIdx.y ? NK : 27;
    int kcnt = kend - kbeg;

    for (int i = lane; i < NK*3; i += 64) sh[i] = shifts[n*NK*3 + i];
    if (lane < NK) sh[NK*3+lane] = psf[lane];
    const float* T = trans + n*12;
    float R00=T[0],R01=T[1],R10=T[4],R11=T[5],R20=T[8],R21=T[9];
    __syncthreads();

    // AABB over THIS GROUP's tap shifts (lane-parallel min/max)
    int kl = kbeg + ((lane < kcnt) ? lane : 0);
    float sx0 = sh[kl*3], sy0 = sh[kl*3+1], sz0 = sh[kl*3+2];
    float sxmn=sx0,sxmx=sx0,symn=sy0,symx=sy0,szmn=sz0,szmx=sz0;
    for (int o = 32; o; o >>= 1) {
        sxmn = fminf(sxmn, __shfl_xor(sxmn,o)); sxmx = fmaxf(sxmx, __shfl_xor(sxmx,o));
        symn = fminf(symn, __shfl_xor(symn,o)); symx = fmaxf(symx, __shfl_xor(symx,o));
        szmn = fminf(szmn, __shfl_xor(szmn,o)); szmx = fmaxf(szmx, __shfl_xor(szmx,o));
    }
    float cbx = ((float)(tw*16) + 7.5f - 63.5f)*1.25f;
    float cby = ((float)(th*16) + 7.5f - 63.5f)*1.25f;
    const float hs = 9.375f;   // 7.5 * 1.25
    float cx = R00*cbx + R01*cby, hx = (fabsf(R00)+fabsf(R01))*hs;
    float cy = R10*cbx + R11*cby, hy = (fabsf(R10)+fabsf(R11))*hs;
    float cz = R20*cbx + R21*cby, hz = (fabsf(R20)+fabsf(R21))*hs;
    int x_lo = (int)floorf(cx-hx+sxmn), x_hi = (int)floorf(cx+hx+sxmx)+1;
    int y_lo = (int)floorf(cy-hy+symn), y_hi = (int)floorf(cy+hy+symx)+1;
    int z_lo = (int)floorf(cz-hz+szmn), z_hi = (int)floorf(cz+hz+szmx)+1;
    int dxs  = x_hi - x_lo + 1;
    dxs |= 1;                         // odd row stride
    int dys  = y_hi - y_lo + 1;
    int dzs  = z_hi - z_lo + 1;
    int dxdy = dxs * dys;
    int total = dxdy * dzs;

    bool safe = (2.5f*(R00 - fabsf(R01)) >= 2.0f) &&
                (2.5f*(R11 - fabsf(R10)) >= 2.0f);

    if (total <= LDSF) {
        for (int c = lane; c < total; c += 64) tile[c] = 0.f;
        __syncthreads();

        // per-phase pixel geometry (fully unrolled -> registers)
        float prbx[4], prby[4], prbz[4], pval[4];
#pragma unroll
        for (int p = 0; p < 4; ++p) {
            int w = tw*16 + 2*(lane & 7)  + (p & 1);
            int h = th*16 + 2*(lane >> 3) + (p >> 1);
            float bx = ((float)w - 63.5f)*1.25f;
            float by = ((float)h - 63.5f)*1.25f;
            prbx[p] = R00*bx + R01*by;
            prby[p] = R10*bx + R11*by;
            prbz[p] = R20*bx + R21*by;
            pval[p] = val[n*16384 + (h<<7) + w];
        }

#pragma unroll 1
        for (int k = kbeg; k < kend; ++k) {
            float sx = sh[k*3], sy = sh[k*3+1], sz = sh[k*3+2], wk = sh[NK*3+k];
#pragma unroll
            for (int p = 0; p < 4; ++p) {
                float x = prbx[p] + sx, y = prby[p] + sy, z = prbz[p] + sz;
                float x0f = floorf(x), y0f = floorf(y), z0f = floorf(z);
                int lx = (int)x0f - x_lo, ly = (int)y0f - y_lo, lz = (int)z0f - z_lo;
                float fx = x - x0f, fy = y - y0f, fz = z - z0f;
                float vw = pval[p] * wk;
                float wx1 = fx, wx0 = 1.f - fx;
                float wy1 = fy, wy0 = 1.f - fy;
                float wz1 = fz, wz0 = 1.f - fz;
                float* q = tile + lz*dxdy + ly*dxs + lx;
                if (safe) {
                    // batched RMW: 8 reads -> 8 adds -> 8 writes (one wait)
                    float t0 = q[0],          t1 = q[1];
                    float t2 = q[dxs],        t3 = q[dxs+1];
                    float t4 = q[dxdy],       t5 = q[dxdy+1];
                    float t6 = q[dxdy+dxs],   t7 = q[dxdy+dxs+1];
                    q[0]          = t0 + vw*wz0*wy0*wx0;
                    q[1]          = t1 + vw*wz0*wy0*wx1;
                    q[dxs]        = t2 + vw*wz0*wy1*wx0;
                    q[dxs+1]      = t3 + vw*wz0*wy1*wx1;
                    q[dxdy]       = t4 + vw*wz1*wy0*wx0;
                    q[dxdy+1]     = t5 + vw*wz1*wy0*wx1;
                    q[dxdy+dxs]   = t6 + vw*wz1*wy1*wx0;
                    q[dxdy+dxs+1] = t7 + vw*wz1*wy1*wx1;
                } else {
                    atomicAdd(q,            vw*wz0*wy0*wx0);
                    atomicAdd(q+1,          vw*wz0*wy0*wx1);
                    atomicAdd(q+dxs,        vw*wz0*wy1*wx0);
                    atomicAdd(q+dxs+1,      vw*wz0*wy1*wx1);
                    atomicAdd(q+dxdy,       vw*wz1*wy0*wx0);
                    atomicAdd(q+dxdy+1,     vw*wz1*wy0*wx1);
                    atomicAdd(q+dxdy+dxs,   vw*wz1*wy1*wx0);
                    atomicAdd(q+dxdy+dxs+1, vw*wz1*wy1*wx1);
                }
            }
        }
        __syncthreads();

        for (int c = lane; c < total; c += 64) {
            float v2 = tile[c];
            if (v2 != 0.f) {
                int lz = c / dxdy;
                int rem = c - lz*dxdy;
                int ly = rem / dxs;
                int lx = rem - ly*dxs;
                int gx = x_lo+lx, gy = y_lo+ly, gz = z_lo+lz;
                if (((unsigned)gx < 128u) & ((unsigned)gy < 128u) & ((unsigned)gz < 128u))
                    unsafeAtomicAdd(pout + gz*16384 + gy*128 + gx, v2);
            }
        }
    } else {
        // fallback: direct global-atomic splat for THIS GROUP's taps
        for (int s2 = 0; s2 < 4; ++s2) {
            int px = s2*64 + lane;
            int ty = px >> 4, tx = px & 15;
            int h = th*16 + ty, w = tw*16 + tx;
            float bx = ((float)w - 63.5f)*1.25f;
            float by = ((float)h - 63.5f)*1.25f;
            float rbx = R00*bx + R01*by;
            float rby = R10*bx + R11*by;
            float rbz = R20*bx + R21*by;
            float v = val[n*16384 + (h<<7) + w];
#pragma unroll 1
            for (int k = kbeg; k < kend; ++k)
                trilerp_splat_g(pout, rbx + sh[k*3], rby + sh[k*3+1],
                                rbz + sh[k*3+2], sh[NK*3+k] * v);
        }
    }
}

// ---------------------------------------------------------------------------
// CG vector updates
__global__ __launch_bounds__(256) void k_init(const float* __restrict__ b,
                                              const float* __restrict__ Ax,
                                              float* __restrict__ r,
                                              float* __restrict__ p,
                                              double* rr0)
{
    double s = 0.0;
    for (int i = blockIdx.x * blockDim.x + threadIdx.x; i < NVOX;
         i += gridDim.x * blockDim.x) {
        float rv = b[i] - Ax[i];
        r[i] = rv;
        p[i] = rv;
        s += (double)rv * (double)rv;
    }
    block_reduce_add(s, rr0);
}

__global__ __launch_bounds__(256) void k_update_xr(float* __restrict__ x,
                                                   float* __restrict__ r,
                                                   const float* __restrict__ p,
                                                   const float* __restrict__ Ap,
                                                   const double* rr, const double* pap,
                                                   double* rrn, int do_r)
{
    float alpha = (float)(rr[0] / pap[0]);
    double s = 0.0;
    for (int i = blockIdx.x * blockDim.x + threadIdx.x; i < NVOX;
         i += gridDim.x * blockDim.x) {
        x[i] += alpha * p[i];
        if (do_r) {
            float rn = r[i] - alpha * Ap[i];
            r[i] = rn;
            s += (double)rn * (double)rn;
        }
    }
    block_reduce_add(s, rrn);
}

__global__ __launch_bounds__(256) void k_update_p(float* __restrict__ p,
                                                  const float* __restrict__ r,
                                                  const double* rrn, const double* rro)
{
    float beta = (float)(rrn[0] / rro[0]);
    for (int i = blockIdx.x * blockDim.x + threadIdx.x; i < NVOX;
         i += gridDim.x * blockDim.x)
        p[i] = r[i] + beta * p[i];
}

__global__ __launch_bounds__(256) void k_relu(const float* __restrict__ x,
                                              float* __restrict__ out)
{
    for (int i = blockIdx.x * blockDim.x + threadIdx.x; i < NVOX;
         i += gridDim.x * blockDim.x)
        out[i] = fmaxf(x[i], 0.f);
}

// ---------------------------------------------------------------------------
extern "C" void kernel_launch(void* const* d_in, const int* in_sizes, int n_in,
                              void* d_out, int out_size, void* d_ws, size_t ws_size,
                              hipStream_t stream)
{
    const float* vol    = (const float*)d_in[0];   // 128^3
    const float* slices = (const float*)d_in[1];   // 48*128*128
    const float* trans  = (const float*)d_in[2];   // 48*3*4
    const float* psf    = (const float*)d_in[3];   // 45
    float* out = (float*)d_out;

    const size_t VB = (size_t)NVOX * 4;            // 8 MB
    char* w = (char*)d_ws;
    float* x      = (float*)(w);
    float* b      = (float*)(w + VB);
    float* r      = (float*)(w + VB*2);
    float* p      = (float*)(w + VB*3);
    float* Ap     = (float*)(w + VB*4);
    float* shifts = (float*)(w + VB*5);            // 25920 B
    double* sc    = (double*)(w + VB*5 + 32768);   // 22 doubles
    float* val    = (float*)(w + VB*6);            // 48*16384 floats = 3 MB
    // sc[0..10] = rr_i, sc[11..20] = pAp_i, sc[21] = dummy pAp for initial AtA

    hipMemsetAsync(sc, 0, 22 * sizeof(double), stream);
    hipLaunchKernelGGL(k_shifts, dim3(9), dim3(256), 0, stream, trans, shifts);

    // b = At(y): slices already have the val layout — splat directly
    hipMemsetAsync(b, 0, VB, stream);
    hipLaunchKernelGGL(k_splat, dim3(NSL * 64, 2), dim3(64), 0, stream,
                       slices, b, shifts, psf, trans);

    // x = vol (initial guess)
    hipMemcpyAsync(x, vol, VB, hipMemcpyDeviceToDevice, stream);

    // Ax = AtA(x)  (k_gather zeroes Ap and computes a dummy pAp)
    hipLaunchKernelGGL(k_gather, dim3(NSL * 64), dim3(256), 0, stream,
                       x, shifts, psf, trans, val, (float4*)Ap, sc + 21);
    hipLaunchKernelGGL(k_splat, dim3(NSL * 64, 2), dim3(64), 0, stream,
                       val, Ap, shifts, psf, trans);

    // r = b - Ax; p = r; rr0 = <r,r>
    hipLaunchKernelGGL(k_init, dim3(512), dim3(256), 0, stream, b, Ap, r, p, sc + 0);

    for (int i = 0; i < 10; ++i) {
        // gather: val = A p, Ap := 0, pAp_i = sum(val^2) == <p, AtA p>
        hipLaunchKernelGGL(k_gather, dim3(NSL * 64), dim3(256), 0, stream,
                           p, shifts, psf, trans, val, (float4*)Ap, sc + 11 + i);
        hipLaunchKernelGGL(k_splat, dim3(NSL * 64, 2), dim3(64), 0, stream,
                           val, Ap, shifts, psf, trans);
        hipLaunchKernelGGL(k_update_xr, dim3(512), dim3(256), 0, stream,
                           x, r, p, Ap, sc + i, sc + 11 + i, sc + i + 1, (int)(i < 9));
        if (i < 9)
            hipLaunchKernelGGL(k_update_p, dim3(512), dim3(256), 0, stream,
                               p, r, sc + i + 1, sc + i);
    }

    hipLaunchKernelGGL(k_relu, dim3(512), dim3(256), 0, stream, x, out);
}